// Round 13
// baseline (523.366 us; speedup 1.0000x reference)
//
#include <hip/hip_runtime.h>
#include <hip/hip_bf16.h>
#include <math.h>

typedef __attribute__((ext_vector_type(8))) short bf16x8;
typedef __attribute__((ext_vector_type(4))) float f32x4;
typedef __attribute__((ext_vector_type(16))) float f32x16;
typedef __attribute__((ext_vector_type(8))) unsigned short u16x8;
typedef __attribute__((ext_vector_type(4))) unsigned short u16x4;

static constexpr int B = 4, S = 2048, D = 2048, H = 16, DH = 128;
static constexpr int N3 = 3 * D;   // 6144
static constexpr int M = B * S;    // 8192

__device__ __forceinline__ unsigned short f2bf(float f) {
  unsigned u = __float_as_uint(f);
  u += 0x7fffu + ((u >> 16) & 1u);
  return (unsigned short)(u >> 16);
}
__device__ __forceinline__ float bf2f(unsigned short b) {
  return __uint_as_float(((unsigned)b) << 16);
}

// ---------------- elementwise f32 -> bf16 convert (vectorized) ----------------
__global__ __launch_bounds__(256) void cvt_kernel(const float* __restrict__ in,
                                                  unsigned short* __restrict__ out) {
  size_t i = (size_t)blockIdx.x * 256 + threadIdx.x;
  f32x4 v = *(const f32x4*)(in + i * 4);
  u16x4 o;
  o[0] = f2bf(v[0]); o[1] = f2bf(v[1]); o[2] = f2bf(v[2]); o[3] = f2bf(v[3]);
  *(u16x4*)(out + i * 4) = o;
}

// ---------------- tiled transpose-convert: W (K,N) f32 -> WT (N,K) bf16 ----------------
__global__ __launch_bounds__(256) void transpose_kernel(const float* __restrict__ W,
                                                        unsigned short* __restrict__ WT,
                                                        int K, int N) {
  __shared__ float t[32][33];
  int tx = threadIdx.x, ty = threadIdx.y;
  int n0 = blockIdx.x * 32, k0 = blockIdx.y * 32;
#pragma unroll
  for (int i = 0; i < 4; i++)
    t[ty + i * 8][tx] = W[(size_t)(k0 + ty + i * 8) * N + n0 + tx];
  __syncthreads();
#pragma unroll
  for (int i = 0; i < 4; i++)
    WT[(size_t)(n0 + ty + i * 8) * K + k0 + tx] = f2bf(t[tx][ty + i * 8]);
}

// ---------------- async global->LDS helper ----------------
__device__ __forceinline__ void gload_lds(const void* g, void* l) {
  __builtin_amdgcn_global_load_lds((const __attribute__((address_space(1))) void*)g,
                                   (__attribute__((address_space(3))) void*)l, 16, 0, 0);
}

// ---------------- bf16 MFMA GEMM, 256x256 tile, 4-phase pipeline, 32x32x16 MFMA -------
// Same banked 4-phase skeleton as the 231-us kernel (BK=64, 2 LDS dbuf, per-phase
// vmcnt(4)), but MFMA shape swapped 16x16x32 -> 32x32x16 (higher pipe rate: 2382 vs
// 2075 TF ubench; half the MFMA instruction count). Same LDS layout/staging/swizzle;
// for 32x32 frag reads the swizzle reduces to ((ks*2+hi)^((ql>>1)&3)) -> 2-way max
// bank aliasing (free). C/D: col=lane&31, row=(reg&3)+8*(reg>>2)+4*(lane>>5).
// NOTE: do NOT cap occupancy via __launch_bounds__ 2nd arg (round-10: VGPR=64 spill).
template <int EPI>
__global__ __launch_bounds__(512, 1) void gemm_bt(
    const unsigned short* __restrict__ A, const unsigned short* __restrict__ Bt,
    const float* __restrict__ bias, float* __restrict__ Cf,
    unsigned short* __restrict__ Qp, unsigned short* __restrict__ Kp,
    unsigned short* __restrict__ VTp, int Nn, int nbn) {
  __shared__ __align__(16) unsigned short lds[65536];  // 128 KiB
  constexpr int NT = 32;  // K = 2048 / BK = 64
  const int tid = threadIdx.x;
  const int l = tid & 63;
  const int w = tid >> 6;
  const int ql = l & 31, hi = l >> 5;
  const int wm = w >> 2, wn = w & 3;

  const int nwg = gridDim.x;
  const int cpx = nwg >> 3;
  const int wg = blockIdx.x;
  const int swz = (wg & 7) * cpx + (wg >> 3);
  const int bm = swz / nbn;
  const int bn = swz - bm * nbn;

  // ---- staging setup (per thread): 1 A-chunk + 1 B-chunk per phase ----
  const int lq = l >> 2, lg = l & 3;
  const int gsw = lg ^ ((l >> 3) & 3);  // pre-swizzled source granule
  const unsigned short* sA[2];
  const unsigned short* sB[2];
  int dA[2], dB[2];
#pragma unroll
  for (int mh = 0; mh < 2; mh++) {
    const int rowA = mh * 64 + wn * 16 + lq;
    sA[mh] = A + (size_t)(bm * 256 + wm * 128 + rowA) * 2048 + gsw * 8;
    dA[mh] = wm * 8192 + rowA * 32 + lg * 8;
    const int rowB = (wm * 2 + (wn & 1)) * 32 + mh * 16 + lq;
    sB[mh] = Bt + (size_t)(bn * 256 + (wn >> 1) * 128 + rowB) * 2048 + gsw * 8;
    dB[mh] = 32768 + (wn >> 1) * 8192 + rowB * 32 + lg * 8;
  }

  // ---- 32x32 fragment-read swizzled k-offsets (ks = k-step 0/1 within kh) ----
  const int sx0 = ((0 * 2 + hi) ^ ((ql >> 1) & 3)) * 8;
  const int sx1 = ((1 * 2 + hi) ^ ((ql >> 1) & 3)) * 8;

  f32x16 acc[4][2];
#pragma unroll
  for (int m = 0; m < 4; m++)
#pragma unroll
    for (int n = 0; n < 2; n++) acc[m][n] = (f32x16)0.f;

#define STG(t1, kh, mh)                                                          \
  do {                                                                           \
    const int dbo_ = ((t1) & 1) * 16384 + (kh) * 4096;                           \
    const int ko_ = (t1) * 64 + (kh) * 32;                                       \
    gload_lds(sA[mh] + ko_, lds + dbo_ + dA[mh]);                                \
    gload_lds(sB[mh] + ko_, lds + dbo_ + dB[mh]);                                \
  } while (0)

  // prologue: stage tile 0 fully, drain once, publish
  STG(0, 0, 0); STG(0, 0, 1); STG(0, 1, 0); STG(0, 1, 1);
  __builtin_amdgcn_sched_barrier(0);
  asm volatile("s_waitcnt vmcnt(0)" ::: "memory");
  __builtin_amdgcn_s_barrier();
  __builtin_amdgcn_sched_barrier(0);

  bf16x8 bfr[4];  // [nt*2 + ks]

#define PHASE(db, kh, mh, DOSTG, t1)                                             \
  do {                                                                           \
    const int AB_ = (db) * 16384 + wm * 8192 + (kh) * 4096 + (mh) * 2048 + ql * 32; \
    bf16x8 a00 = *(const bf16x8*)(lds + AB_ + sx0);                              \
    bf16x8 a01 = *(const bf16x8*)(lds + AB_ + sx1);                              \
    bf16x8 a10 = *(const bf16x8*)(lds + AB_ + 1024 + sx0);                       \
    bf16x8 a11 = *(const bf16x8*)(lds + AB_ + 1024 + sx1);                       \
    if (mh == 0) {                                                               \
      const int BB_ = 32768 + (db) * 16384 + (wn >> 1) * 8192 + (kh) * 4096 +    \
                      (wn & 1) * 2048 + ql * 32;                                 \
      bfr[0] = *(const bf16x8*)(lds + BB_ + sx0);                                \
      bfr[1] = *(const bf16x8*)(lds + BB_ + sx1);                                \
      bfr[2] = *(const bf16x8*)(lds + BB_ + 1024 + sx0);                         \
      bfr[3] = *(const bf16x8*)(lds + BB_ + 1024 + sx1);                         \
    }                                                                            \
    if (DOSTG) STG(t1, kh, mh);                                                  \
    __builtin_amdgcn_sched_barrier(0);                                           \
    asm volatile("s_waitcnt lgkmcnt(0)" ::: "memory");                           \
    __builtin_amdgcn_sched_barrier(0);                                           \
    __builtin_amdgcn_s_setprio(1);                                               \
    acc[(mh)*2 + 0][0] = __builtin_amdgcn_mfma_f32_32x32x16_bf16(a00, bfr[0], acc[(mh)*2 + 0][0], 0, 0, 0); \
    acc[(mh)*2 + 0][1] = __builtin_amdgcn_mfma_f32_32x32x16_bf16(a00, bfr[2], acc[(mh)*2 + 0][1], 0, 0, 0); \
    acc[(mh)*2 + 1][0] = __builtin_amdgcn_mfma_f32_32x32x16_bf16(a10, bfr[0], acc[(mh)*2 + 1][0], 0, 0, 0); \
    acc[(mh)*2 + 1][1] = __builtin_amdgcn_mfma_f32_32x32x16_bf16(a10, bfr[2], acc[(mh)*2 + 1][1], 0, 0, 0); \
    acc[(mh)*2 + 0][0] = __builtin_amdgcn_mfma_f32_32x32x16_bf16(a01, bfr[1], acc[(mh)*2 + 0][0], 0, 0, 0); \
    acc[(mh)*2 + 0][1] = __builtin_amdgcn_mfma_f32_32x32x16_bf16(a01, bfr[3], acc[(mh)*2 + 0][1], 0, 0, 0); \
    acc[(mh)*2 + 1][0] = __builtin_amdgcn_mfma_f32_32x32x16_bf16(a11, bfr[1], acc[(mh)*2 + 1][0], 0, 0, 0); \
    acc[(mh)*2 + 1][1] = __builtin_amdgcn_mfma_f32_32x32x16_bf16(a11, bfr[3], acc[(mh)*2 + 1][1], 0, 0, 0); \
    __builtin_amdgcn_s_setprio(0);                                               \
    __builtin_amdgcn_sched_barrier(0);                                           \
    asm volatile("s_waitcnt vmcnt(4)" ::: "memory");                             \
    __builtin_amdgcn_s_barrier();                                                \
    __builtin_amdgcn_sched_barrier(0);                                           \
  } while (0)

#pragma unroll 2
  for (int t = 0; t < NT; t++) {
    const int db = t & 1;
    const bool dg = (t + 1) < NT;
    PHASE(db, 0, 0, dg, t + 1);
    PHASE(db, 0, 1, dg, t + 1);
    PHASE(db, 1, 0, dg, t + 1);
    PHASE(db, 1, 1, dg, t + 1);
  }
#undef PHASE
#undef STG

#pragma unroll
  for (int mi = 0; mi < 4; mi++) {
#pragma unroll
    for (int ni = 0; ni < 2; ni++) {
      const int col = bn * 256 + wn * 64 + ni * 32 + ql;
      const float bv = bias[col];
      const int which = col >> 11, within = col & 2047;
      const int hh = within >> 7, d = within & 127;
#pragma unroll
      for (int r = 0; r < 16; r++) {
        const int row = bm * 256 + wm * 128 + mi * 32 + (r & 3) + 8 * (r >> 2) + 4 * hi;
        const float v = acc[mi][ni][r] + bv;
        if (EPI == 0) {
          const unsigned short ob = f2bf(v);
          const int b = row >> 11, s = row & 2047;
          const size_t bh = (size_t)(b * H + hh);
          if (which == 0)      Qp[(bh * S + s) * DH + d] = ob;
          else if (which == 1) Kp[(bh * S + s) * DH + d] = ob;
          else                 VTp[(bh * DH + d) * S + s] = ob;
        } else {
          Cf[(size_t)row * Nn + col] = v;
        }
      }
    }
  }
}

// ---------------- RoPE in-place on (BH, S, DH) bf16, interleaved pairs ----------------
__global__ __launch_bounds__(256) void rope_kernel(unsigned short* __restrict__ T,
                                                   const float* __restrict__ cosT,
                                                   const float* __restrict__ sinT) {
  int t = blockIdx.x * 256 + threadIdx.x;
  int d8 = t & 15;
  int s = (t >> 4) & (S - 1);
  size_t off = (size_t)t * 8;
  u16x8 v = *(const u16x8*)(T + off);
  f32x4 c = *(const f32x4*)(cosT + (size_t)s * (DH / 2) + d8 * 4);
  f32x4 sn = *(const f32x4*)(sinT + (size_t)s * (DH / 2) + d8 * 4);
  u16x8 o;
#pragma unroll
  for (int j = 0; j < 4; j++) {
    float x1 = bf2f(v[2 * j]), x2 = bf2f(v[2 * j + 1]);
    o[2 * j]     = f2bf(x1 * c[j] - x2 * sn[j]);
    o[2 * j + 1] = f2bf(x1 * sn[j] + x2 * c[j]);
  }
  *(u16x8*)(T + off) = o;
}

// ---------------- flash attention v4: KVBLK=64, LDS-shared across 8 waves ----------
__global__ __launch_bounds__(512, 1) void attn4_kernel(
    const unsigned short* __restrict__ Q, const unsigned short* __restrict__ Kt,
    const unsigned short* __restrict__ VT, unsigned short* __restrict__ O) {
  __shared__ __align__(16) unsigned short lK[2][64 * 128];   // 16 KB each
  __shared__ __align__(16) unsigned short lV[2][128 * 72];   // 18 KB each
  const int tid = threadIdx.x;
  const int w = tid >> 6;       // wave 0..7
  const int l = tid & 63;
  const int ql = l & 31;
  const int hi = l >> 5;        // 0/1
  const int j = blockIdx.x;
  const int bh = ((j >> 3) & 7) * 8 + (j & 7);
  const int pr = j >> 6;        // 0..3
  const int b = bh >> 4, h = bh & 15;
  const size_t base = (size_t)bh * S * DH;
  const float cl = 0.088388347648318447f * 1.44269504088896341f;  // (1/sqrt(DH))*log2e

  const unsigned short* Ksrc[2];
  int Kdst[2];
#pragma unroll
  for (int i = 0; i < 2; i++) {
    const int g = i * 512 + tid;
    const int krow = g >> 4;
    Ksrc[i] = Kt + base + (size_t)krow * 128 + (g & 15) * 8;   // + kb*8192
    Kdst[i] = (g * 8) ^ ((krow & 7) << 3);
  }
  const int vdh = tid >> 2;
  const unsigned short* Vsrc = VT + ((size_t)bh * DH + vdh) * S;  // + kb*64 + vcol
  int vcol[2], Vdst[2];
#pragma unroll
  for (int i = 0; i < 2; i++) {
    vcol[i] = (tid & 3) * 8 + i * 32;
    Vdst[i] = vdh * 72 + vcol[i];
  }
  const int sfx = (ql & 7) << 3;

  for (int half = 0; half < 2; half++) {
    const int strip = half ? 7 - pr : pr;
    const int qw0 = strip * 256 + w * 32;

    bf16x8 qf[8];
    const unsigned short* qp = Q + base + (size_t)(qw0 + ql) * DH + hi * 8;
#pragma unroll
    for (int t = 0; t < 8; t++) qf[t] = *(const bf16x8*)(qp + t * 16);

    f32x16 acc[4];
#pragma unroll
    for (int mt = 0; mt < 4; mt++) acc[mt] = (f32x16)0.f;
    float m = -INFINITY, lsum = 0.f;

    const int ntb = 4 * (strip + 1);  // 64-row tiles this block iterates

    {
      f32x4 k0 = *(const f32x4*)(Ksrc[0]);
      f32x4 k1 = *(const f32x4*)(Ksrc[1]);
      f32x4 v0 = *(const f32x4*)(Vsrc + vcol[0]);
      f32x4 v1 = *(const f32x4*)(Vsrc + vcol[1]);
      *(f32x4*)(&lK[0][Kdst[0]]) = k0;
      *(f32x4*)(&lK[0][Kdst[1]]) = k1;
      *(f32x4*)(&lV[0][Vdst[0]]) = v0;
      *(f32x4*)(&lV[0][Vdst[1]]) = v1;
      __syncthreads();
    }

    for (int kb = 0; kb < ntb; kb++) {
      const int cur = kb & 1;
      const bool more = (kb + 1 < ntb);
      f32x4 k0r, k1r, v0r, v1r;
      if (more) {
        k0r = *(const f32x4*)(Ksrc[0] + (size_t)(kb + 1) * 8192);
        k1r = *(const f32x4*)(Ksrc[1] + (size_t)(kb + 1) * 8192);
        v0r = *(const f32x4*)(Vsrc + (kb + 1) * 64 + vcol[0]);
        v1r = *(const f32x4*)(Vsrc + (kb + 1) * 64 + vcol[1]);
      }
      const unsigned short* kbuf = lK[cur];
      const unsigned short* vbuf = lV[cur];
#pragma unroll
      for (int stx = 0; stx < 2; stx++) {
        const int kvs = kb * 64 + stx * 32;
        if (kvs <= qw0) {
          const bool diag = (kvs == qw0);
          const int krb = (stx * 32 + ql) * 128;
          f32x16 s0 = (f32x16)0.f, s1 = (f32x16)0.f;
#pragma unroll
          for (int t = 0; t < 4; t++) {
            bf16x8 k0 = *(const bf16x8*)(kbuf + ((krb + (2 * t) * 16 + 8 * hi) ^ sfx));
            bf16x8 k1 = *(const bf16x8*)(kbuf + ((krb + (2 * t + 1) * 16 + 8 * hi) ^ sfx));
            s0 = __builtin_amdgcn_mfma_f32_32x32x16_bf16(k0, qf[2 * t], s0, 0, 0, 0);
            s1 = __builtin_amdgcn_mfma_f32_32x32x16_bf16(k1, qf[2 * t + 1], s1, 0, 0, 0);
          }
          float sv[16];
#pragma unroll
          for (int r = 0; r < 16; r++) sv[r] = s0[r] + s1[r];
          if (diag) {
#pragma unroll
            for (int r = 0; r < 16; r++) {
              const int klocal = (r & 3) + 8 * (r >> 2) + 4 * hi;
              sv[r] = (klocal > ql) ? -INFINITY : sv[r];
            }
          }
          float smax = sv[0];
#pragma unroll
          for (int r = 1; r < 16; r++) smax = fmaxf(smax, sv[r]);
          smax = fmaxf(smax, __shfl_xor(smax, 32));

          float fr = 1.f;
          if (!__all((smax - m) * cl <= 8.0f)) {
            const float mn = fmaxf(m, smax);
            fr = exp2f((m - mn) * cl);
            m = mn;
#pragma unroll
            for (int mt = 0; mt < 4; mt++)
#pragma unroll
              for (int r = 0; r < 16; r++) acc[mt][r] *= fr;
          }
          float p[16];
          float ps = 0.f;
#pragma unroll
          for (int r = 0; r < 16; r++) {
            p[r] = exp2f((sv[r] - m) * cl);
            ps += p[r];
          }
          lsum = lsum * fr + ps + __shfl_xor(ps, 32);

          unsigned W[8];
#pragma unroll
          for (int qd = 0; qd < 4; qd++) {
            W[2 * qd]     = (unsigned)f2bf(p[4 * qd])     | ((unsigned)f2bf(p[4 * qd + 1]) << 16);
            W[2 * qd + 1] = (unsigned)f2bf(p[4 * qd + 2]) | ((unsigned)f2bf(p[4 * qd + 3]) << 16);
          }
#pragma unroll
          for (int t = 0; t < 2; t++) {
            const unsigned ss0 = hi ? W[4 * t] : W[4 * t + 2];
            const unsigned ss1 = hi ? W[4 * t + 1] : W[4 * t + 3];
            const unsigned r0 = __shfl_xor((int)ss0, 32);
            const unsigned r1 = __shfl_xor((int)ss1, 32);
            union { unsigned u[4]; bf16x8 v; } pf;
            if (hi == 0) { pf.u[0] = W[4 * t]; pf.u[1] = W[4 * t + 1]; pf.u[2] = r0; pf.u[3] = r1; }
            else         { pf.u[0] = r0; pf.u[1] = r1; pf.u[2] = W[4 * t + 2]; pf.u[3] = W[4 * t + 3]; }
#pragma unroll
            for (int mt = 0; mt < 4; mt++) {
              const bf16x8 vf = *(const bf16x8*)(vbuf + (mt * 32 + ql) * 72 + stx * 32 + 16 * t + 8 * hi);
              acc[mt] = __builtin_amdgcn_mfma_f32_32x32x16_bf16(vf, pf.v, acc[mt], 0, 0, 0);
            }
          }
        }
      }
      if (more) {
        *(f32x4*)(&lK[cur ^ 1][Kdst[0]]) = k0r;
        *(f32x4*)(&lK[cur ^ 1][Kdst[1]]) = k1r;
        *(f32x4*)(&lV[cur ^ 1][Vdst[0]]) = v0r;
        *(f32x4*)(&lV[cur ^ 1][Vdst[1]]) = v1r;
      }
      __syncthreads();
    }

    const float inv = 1.f / lsum;
    const int s_glob = qw0 + ql;
    unsigned short* op = O + ((size_t)(b * S + s_glob) * H + h) * DH;
#pragma unroll
    for (int mt = 0; mt < 4; mt++)
#pragma unroll
      for (int g = 0; g < 4; g++) {
        u16x4 ov;
#pragma unroll
        for (int jj = 0; jj < 4; jj++) ov[jj] = f2bf(acc[mt][4 * g + jj] * inv);
        *(u16x4*)(op + mt * 32 + 8 * g + 4 * hi) = ov;
      }
  }
}

extern "C" void kernel_launch(void* const* d_in, const int* in_sizes, int n_in,
                              void* d_out, int out_size, void* d_ws, size_t ws_size,
                              hipStream_t stream) {
  const float* x    = (const float*)d_in[0];
  const float* cosT = (const float*)d_in[1];
  const float* sinT = (const float*)d_in[2];
  const float* Wqkv = (const float*)d_in[3];
  const float* bqkv = (const float*)d_in[4];
  const float* Wout = (const float*)d_in[5];
  const float* bout = (const float*)d_in[6];

  char* ws = (char*)d_ws;
  unsigned short* xbf   = (unsigned short*)(ws);
  unsigned short* WqkvT = (unsigned short*)(ws + ((size_t)32 << 20));
  unsigned short* WoutT = (unsigned short*)(ws + ((size_t)56 << 20));
  unsigned short* VTb   = (unsigned short*)(ws + ((size_t)64 << 20));
  unsigned short* Qb = (unsigned short*)d_out;
  unsigned short* Kb = (unsigned short*)d_out + (size_t)M * D;
  unsigned short* Ob = xbf;

  cvt_kernel<<<M * D / 1024, 256, 0, stream>>>(x, xbf);
  transpose_kernel<<<dim3(N3 / 32, D / 32), dim3(32, 8), 0, stream>>>(Wqkv, WqkvT, D, N3);
  transpose_kernel<<<dim3(D / 32, D / 32), dim3(32, 8), 0, stream>>>(Wout, WoutT, D, D);
  gemm_bt<0><<<dim3((M / 256) * (N3 / 256)), 512, 0, stream>>>(xbf, WqkvT, bqkv, nullptr,
                                                               Qb, Kb, VTb, N3, N3 / 256);
  rope_kernel<<<(B * H * S * 16) / 256, 256, 0, stream>>>(Qb, cosT, sinT);
  rope_kernel<<<(B * H * S * 16) / 256, 256, 0, stream>>>(Kb, cosT, sinT);
  attn4_kernel<<<B * H * 4, 512, 0, stream>>>(Qb, Kb, VTb, Ob);
  gemm_bt<1><<<dim3((M / 256) * (D / 256)), 512, 0, stream>>>(Ob, WoutT, bout, (float*)d_out,
                                                              nullptr, nullptr, nullptr, D, D / 256);
}

// Round 14
// 483.912 us; speedup vs baseline: 1.0815x; 1.0815x over previous
//
#include <hip/hip_runtime.h>
#include <hip/hip_bf16.h>
#include <math.h>

typedef __attribute__((ext_vector_type(8))) short bf16x8;
typedef __attribute__((ext_vector_type(4))) float f32x4;
typedef __attribute__((ext_vector_type(16))) float f32x16;
typedef __attribute__((ext_vector_type(8))) unsigned short u16x8;
typedef __attribute__((ext_vector_type(4))) unsigned short u16x4;

static constexpr int B = 4, S = 2048, D = 2048, H = 16, DH = 128;
static constexpr int N3 = 3 * D;   // 6144
static constexpr int M = B * S;    // 8192

__device__ __forceinline__ unsigned short f2bf(float f) {
  unsigned u = __float_as_uint(f);
  u += 0x7fffu + ((u >> 16) & 1u);
  return (unsigned short)(u >> 16);
}
__device__ __forceinline__ float bf2f(unsigned short b) {
  return __uint_as_float(((unsigned)b) << 16);
}

// ---------------- elementwise f32 -> bf16 convert (vectorized) ----------------
__global__ __launch_bounds__(256) void cvt_kernel(const float* __restrict__ in,
                                                  unsigned short* __restrict__ out) {
  size_t i = (size_t)blockIdx.x * 256 + threadIdx.x;
  f32x4 v = *(const f32x4*)(in + i * 4);
  u16x4 o;
  o[0] = f2bf(v[0]); o[1] = f2bf(v[1]); o[2] = f2bf(v[2]); o[3] = f2bf(v[3]);
  *(u16x4*)(out + i * 4) = o;
}

// ---------------- tiled transpose-convert: W (K,N) f32 -> WT (N,K) bf16 ----------------
__global__ __launch_bounds__(256) void transpose_kernel(const float* __restrict__ W,
                                                        unsigned short* __restrict__ WT,
                                                        int K, int N) {
  __shared__ float t[32][33];
  int tx = threadIdx.x, ty = threadIdx.y;
  int n0 = blockIdx.x * 32, k0 = blockIdx.y * 32;
#pragma unroll
  for (int i = 0; i < 4; i++)
    t[ty + i * 8][tx] = W[(size_t)(k0 + ty + i * 8) * N + n0 + tx];
  __syncthreads();
#pragma unroll
  for (int i = 0; i < 4; i++)
    WT[(size_t)(n0 + ty + i * 8) * K + k0 + tx] = f2bf(t[tx][ty + i * 8]);
}

// ---------------- async global->LDS helper ----------------
__device__ __forceinline__ void gload_lds(const void* g, void* l) {
  __builtin_amdgcn_global_load_lds((const __attribute__((address_space(1))) void*)g,
                                   (__attribute__((address_space(3))) void*)l, 16, 0, 0);
}

// ---------------- bf16 MFMA GEMM, 256x256 tile, 4-phase pipeline (best measured) ------
// Benched 231-232 us (MfmaUtil 40.2%, 0 bank conflicts): BK=64, 2 LDS dbuf (128 KiB),
// 4 phases/tile = (kh,mh): {A-frags (+B if mh==0) ds_read; 2 gload_lds stage t+1;
// lgkm(0); setprio1; 16x mfma_16x16x32; setprio0; vmcnt(4); s_barrier}.
// Measured-dead ends (do not revisit): 32x32x16 frag swap (r13: swizzle breaks, 18.9M
// conflicts, 261us); occupancy cap via __launch_bounds__(512,4) (r10: VGPR=64 -> acc
// spills, 4.7GB scratch, 2007us); RoPE in epilogue (r9: +37us, scattered table reads);
// 3-buf/8-phase/frag-dbuf schedules (r5-r8: all 238-270us).
template <int EPI>
__global__ __launch_bounds__(512, 1) void gemm_bt(
    const unsigned short* __restrict__ A, const unsigned short* __restrict__ Bt,
    const float* __restrict__ bias, float* __restrict__ Cf,
    unsigned short* __restrict__ Qp, unsigned short* __restrict__ Kp,
    unsigned short* __restrict__ VTp, int Nn, int nbn) {
  __shared__ __align__(16) unsigned short lds[65536];  // 128 KiB
  constexpr int NT = 32;  // K = 2048 / BK = 64
  const int tid = threadIdx.x;
  const int l = tid & 63;
  const int w = tid >> 6;
  const int lc = l & 15, lr = l >> 4;
  const int wm = w >> 2, wn = w & 3;

  const int nwg = gridDim.x;
  const int cpx = nwg >> 3;
  const int wg = blockIdx.x;
  const int swz = (wg & 7) * cpx + (wg >> 3);
  const int bm = swz / nbn;
  const int bn = swz - bm * nbn;

  const int lq = l >> 2, lg = l & 3;
  const int gsw = lg ^ ((l >> 3) & 3);  // pre-swizzled source granule
  const unsigned short* sA[2];
  const unsigned short* sB[2];
  int dA[2], dB[2];
#pragma unroll
  for (int mh = 0; mh < 2; mh++) {
    const int rowA = mh * 64 + wn * 16 + lq;
    sA[mh] = A + (size_t)(bm * 256 + wm * 128 + rowA) * 2048 + gsw * 8;
    dA[mh] = wm * 8192 + rowA * 32 + lg * 8;
    const int rowB = (wm * 2 + (wn & 1)) * 32 + mh * 16 + lq;
    sB[mh] = Bt + (size_t)(bn * 256 + (wn >> 1) * 128 + rowB) * 2048 + gsw * 8;
    dB[mh] = 32768 + (wn >> 1) * 8192 + rowB * 32 + lg * 8;
  }

  const int rsw = (lr ^ ((lc >> 1) & 3)) * 8;
  const int frA = wm * 8192 + lc * 32 + rsw;
  const int frB = 32768 + (wn >> 1) * 8192 + ((wn & 1) * 64 + lc) * 32 + rsw;

  f32x4 acc[8][4];
#pragma unroll
  for (int m = 0; m < 8; m++)
#pragma unroll
    for (int n = 0; n < 4; n++) acc[m][n] = (f32x4)0.f;

#define STG(t1, kh, mh)                                                          \
  do {                                                                           \
    const int dbo_ = ((t1) & 1) * 16384 + (kh) * 4096;                           \
    const int ko_ = (t1) * 64 + (kh) * 32;                                       \
    gload_lds(sA[mh] + ko_, lds + dbo_ + dA[mh]);                                \
    gload_lds(sB[mh] + ko_, lds + dbo_ + dB[mh]);                                \
  } while (0)

  STG(0, 0, 0); STG(0, 0, 1); STG(0, 1, 0); STG(0, 1, 1);
  __builtin_amdgcn_sched_barrier(0);
  asm volatile("s_waitcnt vmcnt(0)" ::: "memory");
  __builtin_amdgcn_s_barrier();
  __builtin_amdgcn_sched_barrier(0);

  bf16x8 bfr[4];

#define PHASE(db, kh, mh, DOSTG, t1)                                             \
  do {                                                                           \
    bf16x8 af0, af1, af2, af3;                                                   \
    const int ab_ = (db) * 16384 + (kh) * 4096 + frA + (mh) * 2048;              \
    af0 = *(const bf16x8*)(lds + ab_);                                           \
    af1 = *(const bf16x8*)(lds + ab_ + 512);                                     \
    af2 = *(const bf16x8*)(lds + ab_ + 1024);                                    \
    af3 = *(const bf16x8*)(lds + ab_ + 1536);                                    \
    if (mh == 0) {                                                               \
      const int bb_ = (db) * 16384 + (kh) * 4096 + frB;                          \
      bfr[0] = *(const bf16x8*)(lds + bb_);                                      \
      bfr[1] = *(const bf16x8*)(lds + bb_ + 512);                                \
      bfr[2] = *(const bf16x8*)(lds + bb_ + 1024);                               \
      bfr[3] = *(const bf16x8*)(lds + bb_ + 1536);                               \
    }                                                                            \
    if (DOSTG) STG(t1, kh, mh);                                                  \
    __builtin_amdgcn_sched_barrier(0);                                           \
    asm volatile("s_waitcnt lgkmcnt(0)" ::: "memory");                           \
    __builtin_amdgcn_sched_barrier(0);                                           \
    __builtin_amdgcn_s_setprio(1);                                               \
    _Pragma("unroll")                                                            \
    for (int nt = 0; nt < 4; nt++) {                                             \
      acc[(mh)*4 + 0][nt] = __builtin_amdgcn_mfma_f32_16x16x32_bf16(af0, bfr[nt], acc[(mh)*4 + 0][nt], 0, 0, 0); \
      acc[(mh)*4 + 1][nt] = __builtin_amdgcn_mfma_f32_16x16x32_bf16(af1, bfr[nt], acc[(mh)*4 + 1][nt], 0, 0, 0); \
      acc[(mh)*4 + 2][nt] = __builtin_amdgcn_mfma_f32_16x16x32_bf16(af2, bfr[nt], acc[(mh)*4 + 2][nt], 0, 0, 0); \
      acc[(mh)*4 + 3][nt] = __builtin_amdgcn_mfma_f32_16x16x32_bf16(af3, bfr[nt], acc[(mh)*4 + 3][nt], 0, 0, 0); \
    }                                                                            \
    __builtin_amdgcn_s_setprio(0);                                               \
    __builtin_amdgcn_sched_barrier(0);                                           \
    asm volatile("s_waitcnt vmcnt(4)" ::: "memory");                             \
    __builtin_amdgcn_s_barrier();                                                \
    __builtin_amdgcn_sched_barrier(0);                                           \
  } while (0)

#pragma unroll 2
  for (int t = 0; t < NT; t++) {
    const int db = t & 1;
    const bool dg = (t + 1) < NT;
    PHASE(db, 0, 0, dg, t + 1);
    PHASE(db, 0, 1, dg, t + 1);
    PHASE(db, 1, 0, dg, t + 1);
    PHASE(db, 1, 1, dg, t + 1);
  }
#undef PHASE
#undef STG

#pragma unroll
  for (int m = 0; m < 8; m++) {
#pragma unroll
    for (int n = 0; n < 4; n++) {
      const int col = bn * 256 + wn * 64 + n * 16 + lc;
      const float bv = bias[col];
#pragma unroll
      for (int r = 0; r < 4; r++) {
        const int row = bm * 256 + wm * 128 + (m >> 2) * 64 + (m & 3) * 16 + lr * 4 + r;
        const float v = acc[m][n][r] + bv;
        if (EPI == 0) {
          const unsigned short ob = f2bf(v);
          const int b = row >> 11, s = row & 2047;
          const int which = col >> 11, within = col & 2047;
          const int h = within >> 7, d = within & 127;
          const size_t bh = (size_t)(b * H + h);
          if (which == 0)      Qp[(bh * S + s) * DH + d] = ob;
          else if (which == 1) Kp[(bh * S + s) * DH + d] = ob;
          else                 VTp[(bh * DH + d) * S + s] = ob;
        } else {
          Cf[(size_t)row * Nn + col] = v;
        }
      }
    }
  }
}

// ---------------- RoPE in-place on (2*BH, S, DH) bf16 (Q and K contiguous) ------------
// Indexing is invariant to the leading bh index (each bh block is S*DH elements), so
// one launch with doubled grid ropes both Q and K.
__global__ __launch_bounds__(256) void rope_kernel(unsigned short* __restrict__ T,
                                                   const float* __restrict__ cosT,
                                                   const float* __restrict__ sinT) {
  int t = blockIdx.x * 256 + threadIdx.x;
  int d8 = t & 15;
  int s = (t >> 4) & (S - 1);
  size_t off = (size_t)t * 8;
  u16x8 v = *(const u16x8*)(T + off);
  f32x4 c = *(const f32x4*)(cosT + (size_t)s * (DH / 2) + d8 * 4);
  f32x4 sn = *(const f32x4*)(sinT + (size_t)s * (DH / 2) + d8 * 4);
  u16x8 o;
#pragma unroll
  for (int j = 0; j < 4; j++) {
    float x1 = bf2f(v[2 * j]), x2 = bf2f(v[2 * j + 1]);
    o[2 * j]     = f2bf(x1 * c[j] - x2 * sn[j]);
    o[2 * j + 1] = f2bf(x1 * sn[j] + x2 * c[j]);
  }
  *(u16x8*)(T + off) = o;
}

// ---------------- flash attention v4: KVBLK=64, LDS-shared across 8 waves ----------
__global__ __launch_bounds__(512, 1) void attn4_kernel(
    const unsigned short* __restrict__ Q, const unsigned short* __restrict__ Kt,
    const unsigned short* __restrict__ VT, unsigned short* __restrict__ O) {
  __shared__ __align__(16) unsigned short lK[2][64 * 128];   // 16 KB each
  __shared__ __align__(16) unsigned short lV[2][128 * 72];   // 18 KB each
  const int tid = threadIdx.x;
  const int w = tid >> 6;       // wave 0..7
  const int l = tid & 63;
  const int ql = l & 31;
  const int hi = l >> 5;        // 0/1
  const int j = blockIdx.x;
  const int bh = ((j >> 3) & 7) * 8 + (j & 7);
  const int pr = j >> 6;        // 0..3
  const int b = bh >> 4, h = bh & 15;
  const size_t base = (size_t)bh * S * DH;
  const float cl = 0.088388347648318447f * 1.44269504088896341f;  // (1/sqrt(DH))*log2e

  const unsigned short* Ksrc[2];
  int Kdst[2];
#pragma unroll
  for (int i = 0; i < 2; i++) {
    const int g = i * 512 + tid;
    const int krow = g >> 4;
    Ksrc[i] = Kt + base + (size_t)krow * 128 + (g & 15) * 8;   // + kb*8192
    Kdst[i] = (g * 8) ^ ((krow & 7) << 3);
  }
  const int vdh = tid >> 2;
  const unsigned short* Vsrc = VT + ((size_t)bh * DH + vdh) * S;  // + kb*64 + vcol
  int vcol[2], Vdst[2];
#pragma unroll
  for (int i = 0; i < 2; i++) {
    vcol[i] = (tid & 3) * 8 + i * 32;
    Vdst[i] = vdh * 72 + vcol[i];
  }
  const int sfx = (ql & 7) << 3;

  for (int half = 0; half < 2; half++) {
    const int strip = half ? 7 - pr : pr;
    const int qw0 = strip * 256 + w * 32;

    bf16x8 qf[8];
    const unsigned short* qp = Q + base + (size_t)(qw0 + ql) * DH + hi * 8;
#pragma unroll
    for (int t = 0; t < 8; t++) qf[t] = *(const bf16x8*)(qp + t * 16);

    f32x16 acc[4];
#pragma unroll
    for (int mt = 0; mt < 4; mt++) acc[mt] = (f32x16)0.f;
    float m = -INFINITY, lsum = 0.f;

    const int ntb = 4 * (strip + 1);  // 64-row tiles this block iterates

    {
      f32x4 k0 = *(const f32x4*)(Ksrc[0]);
      f32x4 k1 = *(const f32x4*)(Ksrc[1]);
      f32x4 v0 = *(const f32x4*)(Vsrc + vcol[0]);
      f32x4 v1 = *(const f32x4*)(Vsrc + vcol[1]);
      *(f32x4*)(&lK[0][Kdst[0]]) = k0;
      *(f32x4*)(&lK[0][Kdst[1]]) = k1;
      *(f32x4*)(&lV[0][Vdst[0]]) = v0;
      *(f32x4*)(&lV[0][Vdst[1]]) = v1;
      __syncthreads();
    }

    for (int kb = 0; kb < ntb; kb++) {
      const int cur = kb & 1;
      const bool more = (kb + 1 < ntb);
      f32x4 k0r, k1r, v0r, v1r;
      if (more) {
        k0r = *(const f32x4*)(Ksrc[0] + (size_t)(kb + 1) * 8192);
        k1r = *(const f32x4*)(Ksrc[1] + (size_t)(kb + 1) * 8192);
        v0r = *(const f32x4*)(Vsrc + (kb + 1) * 64 + vcol[0]);
        v1r = *(const f32x4*)(Vsrc + (kb + 1) * 64 + vcol[1]);
      }
      const unsigned short* kbuf = lK[cur];
      const unsigned short* vbuf = lV[cur];
#pragma unroll
      for (int stx = 0; stx < 2; stx++) {
        const int kvs = kb * 64 + stx * 32;
        if (kvs <= qw0) {
          const bool diag = (kvs == qw0);
          const int krb = (stx * 32 + ql) * 128;
          f32x16 s0 = (f32x16)0.f, s1 = (f32x16)0.f;
#pragma unroll
          for (int t = 0; t < 4; t++) {
            bf16x8 k0 = *(const bf16x8*)(kbuf + ((krb + (2 * t) * 16 + 8 * hi) ^ sfx));
            bf16x8 k1 = *(const bf16x8*)(kbuf + ((krb + (2 * t + 1) * 16 + 8 * hi) ^ sfx));
            s0 = __builtin_amdgcn_mfma_f32_32x32x16_bf16(k0, qf[2 * t], s0, 0, 0, 0);
            s1 = __builtin_amdgcn_mfma_f32_32x32x16_bf16(k1, qf[2 * t + 1], s1, 0, 0, 0);
          }
          float sv[16];
#pragma unroll
          for (int r = 0; r < 16; r++) sv[r] = s0[r] + s1[r];
          if (diag) {
#pragma unroll
            for (int r = 0; r < 16; r++) {
              const int klocal = (r & 3) + 8 * (r >> 2) + 4 * hi;
              sv[r] = (klocal > ql) ? -INFINITY : sv[r];
            }
          }
          float smax = sv[0];
#pragma unroll
          for (int r = 1; r < 16; r++) smax = fmaxf(smax, sv[r]);
          smax = fmaxf(smax, __shfl_xor(smax, 32));

          float fr = 1.f;
          if (!__all((smax - m) * cl <= 8.0f)) {
            const float mn = fmaxf(m, smax);
            fr = exp2f((m - mn) * cl);
            m = mn;
#pragma unroll
            for (int mt = 0; mt < 4; mt++)
#pragma unroll
              for (int r = 0; r < 16; r++) acc[mt][r] *= fr;
          }
          float p[16];
          float ps = 0.f;
#pragma unroll
          for (int r = 0; r < 16; r++) {
            p[r] = exp2f((sv[r] - m) * cl);
            ps += p[r];
          }
          lsum = lsum * fr + ps + __shfl_xor(ps, 32);

          unsigned W[8];
#pragma unroll
          for (int qd = 0; qd < 4; qd++) {
            W[2 * qd]     = (unsigned)f2bf(p[4 * qd])     | ((unsigned)f2bf(p[4 * qd + 1]) << 16);
            W[2 * qd + 1] = (unsigned)f2bf(p[4 * qd + 2]) | ((unsigned)f2bf(p[4 * qd + 3]) << 16);
          }
#pragma unroll
          for (int t = 0; t < 2; t++) {
            const unsigned ss0 = hi ? W[4 * t] : W[4 * t + 2];
            const unsigned ss1 = hi ? W[4 * t + 1] : W[4 * t + 3];
            const unsigned r0 = __shfl_xor((int)ss0, 32);
            const unsigned r1 = __shfl_xor((int)ss1, 32);
            union { unsigned u[4]; bf16x8 v; } pf;
            if (hi == 0) { pf.u[0] = W[4 * t]; pf.u[1] = W[4 * t + 1]; pf.u[2] = r0; pf.u[3] = r1; }
            else         { pf.u[0] = r0; pf.u[1] = r1; pf.u[2] = W[4 * t + 2]; pf.u[3] = W[4 * t + 3]; }
#pragma unroll
            for (int mt = 0; mt < 4; mt++) {
              const bf16x8 vf = *(const bf16x8*)(vbuf + (mt * 32 + ql) * 72 + stx * 32 + 16 * t + 8 * hi);
              acc[mt] = __builtin_amdgcn_mfma_f32_32x32x16_bf16(vf, pf.v, acc[mt], 0, 0, 0);
            }
          }
        }
      }
      if (more) {
        *(f32x4*)(&lK[cur ^ 1][Kdst[0]]) = k0r;
        *(f32x4*)(&lK[cur ^ 1][Kdst[1]]) = k1r;
        *(f32x4*)(&lV[cur ^ 1][Vdst[0]]) = v0r;
        *(f32x4*)(&lV[cur ^ 1][Vdst[1]]) = v1r;
      }
      __syncthreads();
    }

    const float inv = 1.f / lsum;
    const int s_glob = qw0 + ql;
    unsigned short* op = O + ((size_t)(b * S + s_glob) * H + h) * DH;
#pragma unroll
    for (int mt = 0; mt < 4; mt++)
#pragma unroll
      for (int g = 0; g < 4; g++) {
        u16x4 ov;
#pragma unroll
        for (int jj = 0; jj < 4; jj++) ov[jj] = f2bf(acc[mt][4 * g + jj] * inv);
        *(u16x4*)(op + mt * 32 + 8 * g + 4 * hi) = ov;
      }
  }
}

extern "C" void kernel_launch(void* const* d_in, const int* in_sizes, int n_in,
                              void* d_out, int out_size, void* d_ws, size_t ws_size,
                              hipStream_t stream) {
  const float* x    = (const float*)d_in[0];
  const float* cosT = (const float*)d_in[1];
  const float* sinT = (const float*)d_in[2];
  const float* Wqkv = (const float*)d_in[3];
  const float* bqkv = (const float*)d_in[4];
  const float* Wout = (const float*)d_in[5];
  const float* bout = (const float*)d_in[6];

  char* ws = (char*)d_ws;
  unsigned short* xbf   = (unsigned short*)(ws);
  unsigned short* WqkvT = (unsigned short*)(ws + ((size_t)32 << 20));
  unsigned short* WoutT = (unsigned short*)(ws + ((size_t)56 << 20));
  unsigned short* VTb   = (unsigned short*)(ws + ((size_t)64 << 20));
  unsigned short* Qb = (unsigned short*)d_out;
  unsigned short* Kb = (unsigned short*)d_out + (size_t)M * D;
  unsigned short* Ob = xbf;

  cvt_kernel<<<M * D / 1024, 256, 0, stream>>>(x, xbf);
  transpose_kernel<<<dim3(N3 / 32, D / 32), dim3(32, 8), 0, stream>>>(Wqkv, WqkvT, D, N3);
  transpose_kernel<<<dim3(D / 32, D / 32), dim3(32, 8), 0, stream>>>(Wout, WoutT, D, D);
  gemm_bt<0><<<dim3((M / 256) * (N3 / 256)), 512, 0, stream>>>(xbf, WqkvT, bqkv, nullptr,
                                                               Qb, Kb, VTb, N3, N3 / 256);
  rope_kernel<<<(2 * B * H * S * 16) / 256, 256, 0, stream>>>(Qb, cosT, sinT);  // Q+K contiguous
  attn4_kernel<<<B * H * 4, 512, 0, stream>>>(Qb, Kb, VTb, Ob);
  gemm_bt<1><<<dim3((M / 256) * (D / 256)), 512, 0, stream>>>(Ob, WoutT, bout, (float*)d_out,
                                                              nullptr, nullptr, nullptr, D, D / 256);
}